// Round 5
// baseline (98.020 us; speedup 1.0000x reference)
//
#include <hip/hip_runtime.h>
#include <hip/hip_bf16.h>

#define B_N 4096
#define D_K 2048

typedef __attribute__((ext_vector_type(8))) short bf16x8;
typedef __attribute__((ext_vector_type(4))) float f32x4;

__device__ __forceinline__ unsigned short f2bf(float f) {
    union { __hip_bfloat16 h; unsigned short u; } cv;
    cv.h = __float2bfloat16(f);
    return cv.u;
}

__device__ __forceinline__ void gl_lds16(const unsigned short* g, unsigned short* l) {
    __builtin_amdgcn_global_load_lds(
        (const __attribute__((address_space(1))) unsigned int*)g,
        (__attribute__((address_space(3))) unsigned int*)l,
        16, 0, 0);
}

// ---------------- Kernel 1: row L2-normalize -> bf16 ----------------
__global__ __launch_bounds__(256) void knorm2(const float* __restrict__ C,
                                              const float* __restrict__ S,
                                              unsigned short* __restrict__ Cb,
                                              unsigned short* __restrict__ Sb) {
    int b = blockIdx.x;            // 0..8191
    const float* X;
    unsigned short* Y;
    if (b < B_N) { X = C + (size_t)b * D_K; Y = Cb + (size_t)b * D_K; }
    else         { X = S + (size_t)(b - B_N) * D_K; Y = Sb + (size_t)(b - B_N) * D_K; }
    int tid = threadIdx.x;

    float4 v0 = ((const float4*)X)[tid * 2];
    float4 v1 = ((const float4*)X)[tid * 2 + 1];
    float ss = v0.x*v0.x + v0.y*v0.y + v0.z*v0.z + v0.w*v0.w
             + v1.x*v1.x + v1.y*v1.y + v1.z*v1.z + v1.w*v1.w;
    #pragma unroll
    for (int off = 1; off < 64; off <<= 1) ss += __shfl_xor(ss, off, 64);
    __shared__ float wsum[4];
    if ((tid & 63) == 0) wsum[tid >> 6] = ss;
    __syncthreads();
    float tot = wsum[0] + wsum[1] + wsum[2] + wsum[3];
    float inv = 1.f / fmaxf(sqrtf(tot), 1e-12f);

    bf16x8 o;
    o[0] = (short)f2bf(v0.x * inv); o[1] = (short)f2bf(v0.y * inv);
    o[2] = (short)f2bf(v0.z * inv); o[3] = (short)f2bf(v0.w * inv);
    o[4] = (short)f2bf(v1.x * inv); o[5] = (short)f2bf(v1.y * inv);
    o[6] = (short)f2bf(v1.z * inv); o[7] = (short)f2bf(v1.w * inv);
    *(bf16x8*)(Y + tid * 8) = o;
}

// ---------------- Kernel 2: 256x256 balanced-pipeline GEMM + fused InfoNCE epilogue ----------------
// Tile 256x256, BK=64, 8 waves (2Mx4N), wave tile 128x64. LDS 128 KiB double-buffered,
// 16B-chunk XOR-swizzle by (row&7) via pre-swizzled global source + swizzled ds_read.
// Zigzag Q00 -> Q01 -> Q11 -> Q10. All ds_reads issue pre-barrier >=1 phase before use
// (A double-buffered afA/afB); bE refill is the single post-MFMA read (B0 straddles P0/P3).
// FIFO-derived counted waits; no vmcnt(0)/lgkmcnt(0) in steady state; 7 barriers/tile.

#define BK 64
#define NT (D_K / BK)   /* 32 */

#define BARRIER()  asm volatile("s_barrier" ::: "memory")
#define LGKM(n)    asm volatile("s_waitcnt lgkmcnt(" #n ")" ::: "memory")
#define VMCNT(n)   asm volatile("s_waitcnt vmcnt(" #n ")" ::: "memory")
#define SCHEDB()   __builtin_amdgcn_sched_barrier(0)
#define PRIO1()    __builtin_amdgcn_s_setprio(1)
#define PRIO0()    __builtin_amdgcn_s_setprio(0)

#define LDA_(boff, qm, dst) do { _Pragma("unroll") \
  for (int mf = 0; mf < 4; ++mf) { \
    dst[mf][0] = *(const bf16x8*)(ldsb + (boff) + (qm)*16384 + abase + mf*2048 + c0); \
    dst[mf][1] = *(const bf16x8*)(ldsb + (boff) + (qm)*16384 + abase + mf*2048 + c1); \
  } } while (0)

#define LDB_(boff, p, dst) do { _Pragma("unroll") \
  for (int nf = 0; nf < 2; ++nf) { \
    dst[nf][0] = *(const bf16x8*)(ldsb + (boff) + 32768 + (p)*16384 + bbase + nf*2048 + c0); \
    dst[nf][1] = *(const bf16x8*)(ldsb + (boff) + 32768 + (p)*16384 + bbase + nf*2048 + c1); \
  } } while (0)

#define MMA_(qm, qn, aset, bset) do { _Pragma("unroll") \
  for (int mf = 0; mf < 4; ++mf) { _Pragma("unroll") \
    for (int nf = 0; nf < 2; ++nf) { \
      acc[(qm)*4+mf][(qn)*2+nf] = __builtin_amdgcn_mfma_f32_16x16x32_bf16(aset[mf][0], bset[nf][0], acc[(qm)*4+mf][(qn)*2+nf], 0, 0, 0); \
      acc[(qm)*4+mf][(qn)*2+nf] = __builtin_amdgcn_mfma_f32_16x16x32_bf16(aset[mf][1], bset[nf][1], acc[(qm)*4+mf][(qn)*2+nf], 0, 0, 0); \
    } } } while (0)

// uniform row offsets: A units: q=0 -> rows {0..63}+{128..191}; q=1 -> {64..127}+{192..255}
#define STAGE_A_(boff, q, kk) do { \
  gl_lds16(gA + (size_t)((q) ?  64 : 0)   * D_K + (kk), (unsigned short*)(ldsb + (boff) + (q)*16384 +        tid*16)); \
  gl_lds16(gA + (size_t)((q) ? 192 : 128) * D_K + (kk), (unsigned short*)(ldsb + (boff) + (q)*16384 + 8192 + tid*16)); \
} while (0)

#define STAGE_B_(boff, p, kk) do { \
  gl_lds16(gB + (size_t)((p) ?  32 : 0)   * D_K + (kk), (unsigned short*)(ldsb + (boff) + 32768 + (p)*16384 +        tid*16)); \
  gl_lds16(gB + (size_t)((p) ? 160 : 128) * D_K + (kk), (unsigned short*)(ldsb + (boff) + 32768 + (p)*16384 + 8192 + tid*16)); \
} while (0)

__global__ __launch_bounds__(512, 2) void kgemm8(const unsigned short* __restrict__ Ab,
                                                 const unsigned short* __restrict__ Bb,
                                                 const float* __restrict__ temp,
                                                 float* __restrict__ rowsum,
                                                 float* __restrict__ colsum,
                                                 float* __restrict__ diag) {
    __shared__ __align__(128) char ldsb[131072];   // 128 KiB

    const int tid  = threadIdx.x;
    const int lane = tid & 63;
    const int wid  = tid >> 6;
    const int wm   = wid >> 2;     // 0..1
    const int wn   = wid & 3;      // 0..3

    // bijective XCD swizzle: 256 blocks = 8 XCDs x 32
    int bid = blockIdx.x;
    int swz = (bid & 7) * 32 + (bid >> 3);
    int brow = (swz >> 4) * 256;
    int bcol = (swz & 15) * 256;

    // ---- staging addresses: per-thread base + uniform row offsets at use ----
    const int rr = tid >> 3;                              // 0..63
    const int ch = (((tid & 7) ^ (rr & 7)) << 3);         // pre-swizzled k-chunk
    const unsigned short* gA = Ab + (size_t)(brow + rr) * D_K + ch;
    const unsigned short* gB = Bb + (size_t)(bcol + (rr >> 5) * 64 + (rr & 31)) * D_K + ch;

    // ---- ds_read constants (swizzled) ----
    const int lrow = lane & 15;
    const int kq   = lane >> 4;                 // 0..3
    const int sw   = (lane & 7) << 4;
    const int c0   = ((kq << 4)      ) ^ sw;
    const int c1   = (64 | (kq << 4)) ^ sw;
    const int abase = (wm * 64 + lrow) * 128;
    const int bbase = (wn * 32 + lrow) * 128;

    f32x4 acc[8][4];
    #pragma unroll
    for (int i = 0; i < 8; ++i)
        #pragma unroll
        for (int j = 0; j < 4; ++j) acc[i][j] = (f32x4){0.f, 0.f, 0.f, 0.f};
    bf16x8 afA[4][2];      // A0(t)
    bf16x8 afB[4][2];      // A1(t)
    bf16x8 bE[2][2];       // B0(t)
    bf16x8 bO[2][2];       // B1(t)

    // ---- prologue: tile0 4 units -> buf0; A0,B0 of tile1 -> buf1; seed afA,bE ----
    STAGE_A_(0, 0, 0); STAGE_B_(0, 0, 0); STAGE_A_(0, 1, 0); STAGE_B_(0, 1, 0);
    STAGE_A_(65536, 0, BK); STAGE_B_(65536, 0, BK);
    VMCNT(4);              // tile0's 4 units resident; A0/B0(1) in flight
    BARRIER();
    LDA_(0, 0, afA);       // A0(0)
    LDB_(0, 0, bE);        // B0(0)
    LGKM(0);

    for (int t = 0; t < NT; ++t) {
        const int c  = (t & 1) << 16;
        const int cN = c ^ 65536;
        const int k1 = (t + 1) * BK;
        const int k2 = (t + 2) * BK;
        const bool s1 = (t + 1 < NT);
        const bool s2 = (t + 2 < NT);

        // ---- P0: Q00 = afA x bE ----
        LDB_(c, 1, bO);                 // B1(t)  (consumed P1; queued first)
        LDA_(c, 1, afB);                // A1(t)  (consumed P2/P3)
        if (s1) STAGE_B_(cN, 1, k1);    // stage B1(t+1)
        BARRIER();
        LGKM(12);                       // drain afA,bE; leave bO+afB in flight
        SCHEDB();
        PRIO1(); MMA_(0, 0, afA, bE); PRIO0();
        // (no end barrier needed: P1-pre has only stage to a dead cross-buffer region)

        // ---- P1: Q01 = afA x bO ----
        if (s1) STAGE_A_(cN, 1, k1);    // stage A1(t+1)
        BARRIER();
        LGKM(8);                        // drain bO; leave afB
        SCHEDB();
        PRIO1(); MMA_(0, 1, afA, bO); PRIO0();
        VMCNT(6); BARRIER();            // A0(t+1) writes complete (for P2 read)

        // ---- P2: Q11 = afB x bO ----
        if (s1) LDA_(cN, 0, afA);       // A0(t+1) (consumed next P0)
        if (s2) STAGE_A_(c, 0, k2);     // stage A0(t+2)
        BARRIER();
        if (s1) { LGKM(8); } else { LGKM(0); }   // drain afB
        SCHEDB();
        PRIO1(); MMA_(1, 1, afB, bO); PRIO0();
        VMCNT(6); BARRIER();            // B0(t+1) writes complete (for P3 read)

        // ---- P3: Q10 = afB x bE ----
        if (s2) STAGE_B_(c, 0, k2);     // stage B0(t+2)
        BARRIER();
        PRIO1(); MMA_(1, 0, afB, bE); PRIO0();   // operands proven drained; no wait
        if (s1) LDB_(cN, 0, bE);        // B0(t+1) (post-MFMA: WAR on bE)
        VMCNT(4); BARRIER();            // B1(t+1),A1(t+1) writes complete (for next P0)
    }

    // ------- epilogue: relu*e^t, shifted exp, row/col partial sums, diag -------
    const float scl = expf(temp[0]);
    float cs[4] = {0.f, 0.f, 0.f, 0.f};
    #pragma unroll
    for (int mi = 0; mi < 8; ++mi) {
        float rs[4] = {0.f, 0.f, 0.f, 0.f};
        const int growb = brow + wm * 128 + (mi >> 2) * 64 + (mi & 3) * 16 + kq * 4;
        #pragma unroll
        for (int ni = 0; ni < 4; ++ni) {
            const int gc = bcol + wn * 64 + (ni >> 1) * 32 + (ni & 1) * 16 + lrow;
            #pragma unroll
            for (int j = 0; j < 4; ++j) {
                float v = fmaxf(acc[mi][ni][j], 0.f) * scl;
                if (growb + j == gc) diag[gc] = v;
                float p = expf(v - scl);
                rs[j]  += p;
                cs[ni] += p;
            }
        }
        #pragma unroll
        for (int j = 0; j < 4; ++j) {
            float v = rs[j];
            v += __shfl_xor(v, 1, 64);
            v += __shfl_xor(v, 2, 64);
            v += __shfl_xor(v, 4, 64);
            v += __shfl_xor(v, 8, 64);
            if (lrow == 0) atomicAdd(&rowsum[growb + j], v);
        }
    }
    #pragma unroll
    for (int ni = 0; ni < 4; ++ni) {
        float v = cs[ni];
        v += __shfl_xor(v, 16, 64);
        v += __shfl_xor(v, 32, 64);
        if (kq == 0) atomicAdd(&colsum[bcol + wn * 64 + (ni >> 1) * 32 + (ni & 1) * 16 + lrow], v);
    }
}

// ---------------- Kernel 3: final reduction to scalar loss ----------------
__global__ __launch_bounds__(256) void kfinal(const float* __restrict__ rowsum,
                                              const float* __restrict__ colsum,
                                              const float* __restrict__ diag,
                                              const float* __restrict__ temp,
                                              float* __restrict__ out) {
    int tid = threadIdx.x;
    float M = expf(temp[0]);
    float acc = 0.f;
    for (int i = tid; i < B_N; i += 256) {
        acc += logf(rowsum[i]) + logf(colsum[i]) + 2.f * M - 2.f * diag[i];
    }
    #pragma unroll
    for (int off = 1; off < 64; off <<= 1) acc += __shfl_xor(acc, off, 64);
    __shared__ float wsum[4];
    if ((tid & 63) == 0) wsum[tid >> 6] = acc;
    __syncthreads();
    if (tid == 0) {
        float t = wsum[0] + wsum[1] + wsum[2] + wsum[3];
        out[0] = t * (0.5f / (float)B_N);
    }
}

extern "C" void kernel_launch(void* const* d_in, const int* in_sizes, int n_in,
                              void* d_out, int out_size, void* d_ws, size_t ws_size,
                              hipStream_t stream) {
    const float* Cf   = (const float*)d_in[0];
    const float* Sf   = (const float*)d_in[1];
    const float* temp = (const float*)d_in[2];

    const size_t MATEL = (size_t)B_N * D_K;
    unsigned short* Cb = (unsigned short*)d_ws;            // 16 MB
    unsigned short* Sb = Cb + MATEL;                       // 16 MB
    float* rowsum = (float*)(Sb + MATEL);                  // 16 KB
    float* colsum = rowsum + B_N;
    float* diag   = colsum + B_N;

    hipMemsetAsync(rowsum, 0, 2 * B_N * sizeof(float), stream);
    knorm2<<<2 * B_N, 256, 0, stream>>>(Cf, Sf, Cb, Sb);
    kgemm8<<<256, 512, 0, stream>>>(Cb, Sb, temp, rowsum, colsum, diag);
    kfinal<<<1, 256, 0, stream>>>(rowsum, colsum, diag, temp, (float*)d_out);
}

// Round 6
// 97.122 us; speedup vs baseline: 1.0092x; 1.0092x over previous
//
#include <hip/hip_runtime.h>
#include <hip/hip_bf16.h>

#define B_N 4096
#define D_K 2048

typedef __attribute__((ext_vector_type(8))) short bf16x8;
typedef __attribute__((ext_vector_type(4))) float f32x4;

__device__ __forceinline__ unsigned short f2bf(float f) {
    union { __hip_bfloat16 h; unsigned short u; } cv;
    cv.h = __float2bfloat16(f);
    return cv.u;
}

__device__ __forceinline__ void gl_lds16(const unsigned short* g, unsigned short* l) {
    __builtin_amdgcn_global_load_lds(
        (const __attribute__((address_space(1))) unsigned int*)g,
        (__attribute__((address_space(3))) unsigned int*)l,
        16, 0, 0);
}

// ---------------- Kernel 1: row L2-normalize -> bf16 ----------------
__global__ __launch_bounds__(256) void knorm2(const float* __restrict__ C,
                                              const float* __restrict__ S,
                                              unsigned short* __restrict__ Cb,
                                              unsigned short* __restrict__ Sb) {
    int b = blockIdx.x;            // 0..8191
    const float* X;
    unsigned short* Y;
    if (b < B_N) { X = C + (size_t)b * D_K; Y = Cb + (size_t)b * D_K; }
    else         { X = S + (size_t)(b - B_N) * D_K; Y = Sb + (size_t)(b - B_N) * D_K; }
    int tid = threadIdx.x;

    float4 v0 = ((const float4*)X)[tid * 2];
    float4 v1 = ((const float4*)X)[tid * 2 + 1];
    float ss = v0.x*v0.x + v0.y*v0.y + v0.z*v0.z + v0.w*v0.w
             + v1.x*v1.x + v1.y*v1.y + v1.z*v1.z + v1.w*v1.w;
    #pragma unroll
    for (int off = 1; off < 64; off <<= 1) ss += __shfl_xor(ss, off, 64);
    __shared__ float wsum[4];
    if ((tid & 63) == 0) wsum[tid >> 6] = ss;
    __syncthreads();
    float tot = wsum[0] + wsum[1] + wsum[2] + wsum[3];
    float inv = 1.f / fmaxf(sqrtf(tot), 1e-12f);

    bf16x8 o;
    o[0] = (short)f2bf(v0.x * inv); o[1] = (short)f2bf(v0.y * inv);
    o[2] = (short)f2bf(v0.z * inv); o[3] = (short)f2bf(v0.w * inv);
    o[4] = (short)f2bf(v1.x * inv); o[5] = (short)f2bf(v1.y * inv);
    o[6] = (short)f2bf(v1.z * inv); o[7] = (short)f2bf(v1.w * inv);
    *(bf16x8*)(Y + tid * 8) = o;
}

// ---------------- Kernel 2: 256x256 m201-template GEMM + fused InfoNCE epilogue ----------------
// Faithful 8-phase/2-K-tile port: zigzag Q00->Q01->Q11->Q10 (24 ds_read_b128/tile/wave,
// P3 reads nothing: bE,afB persist), reads issued in-phase pre-barrier, lgkmcnt(8) on the
// 12-read phase, lgkmcnt(0)+sched_barrier before each MFMA cluster, setprio around MFMA,
// ONE vmcnt(6) per K-tile (tail: vmcnt(0)), 2 barriers/phase, 2-K-tile unrolled main loop.
// Stage schedule (lead >= 6 phases, freed-region + boundary-vmcnt invariants verified):
//   P0(t): A1(t+1)->buf(t+1);  P1(t): A0(t+2)->buf(t);  P2(t): B0(t+2);  P3(t): B1(t+2).

#define BK 64
#define NT (D_K / BK)   /* 32 */

#define BARRIER()  asm volatile("s_barrier" ::: "memory")
#define LGKM(n)    asm volatile("s_waitcnt lgkmcnt(" #n ")" ::: "memory")
#define VMCNT(n)   asm volatile("s_waitcnt vmcnt(" #n ")" ::: "memory")
#define SCHEDB()   __builtin_amdgcn_sched_barrier(0)
#define PRIO1()    __builtin_amdgcn_s_setprio(1)
#define PRIO0()    __builtin_amdgcn_s_setprio(0)

#define LDA_(boff, qm, dst) do { _Pragma("unroll") \
  for (int mf = 0; mf < 4; ++mf) { \
    dst[mf][0] = *(const bf16x8*)(ldsb + (boff) + (qm)*16384 + abase + mf*2048 + c0); \
    dst[mf][1] = *(const bf16x8*)(ldsb + (boff) + (qm)*16384 + abase + mf*2048 + c1); \
  } } while (0)

#define LDB_(boff, p, dst) do { _Pragma("unroll") \
  for (int nf = 0; nf < 2; ++nf) { \
    dst[nf][0] = *(const bf16x8*)(ldsb + (boff) + 32768 + (p)*16384 + bbase + nf*2048 + c0); \
    dst[nf][1] = *(const bf16x8*)(ldsb + (boff) + 32768 + (p)*16384 + bbase + nf*2048 + c1); \
  } } while (0)

#define MMA_(qm, qn, aset, bset) do { _Pragma("unroll") \
  for (int mf = 0; mf < 4; ++mf) { _Pragma("unroll") \
    for (int nf = 0; nf < 2; ++nf) { \
      acc[(qm)*4+mf][(qn)*2+nf] = __builtin_amdgcn_mfma_f32_16x16x32_bf16(aset[mf][0], bset[nf][0], acc[(qm)*4+mf][(qn)*2+nf], 0, 0, 0); \
      acc[(qm)*4+mf][(qn)*2+nf] = __builtin_amdgcn_mfma_f32_16x16x32_bf16(aset[mf][1], bset[nf][1], acc[(qm)*4+mf][(qn)*2+nf], 0, 0, 0); \
    } } } while (0)

// A units: q=0 -> global rows {0..63}+{128..191}; q=1 -> {64..127}+{192..255}
#define STAGE_A_(boff, q, kk) do { \
  gl_lds16(gA + (size_t)((q) ?  64 : 0)   * D_K + (kk), (unsigned short*)(ldsb + (boff) + (q)*16384 +        tid*16)); \
  gl_lds16(gA + (size_t)((q) ? 192 : 128) * D_K + (kk), (unsigned short*)(ldsb + (boff) + (q)*16384 + 8192 + tid*16)); \
} while (0)

#define STAGE_B_(boff, p, kk) do { \
  gl_lds16(gB + (size_t)((p) ?  32 : 0)   * D_K + (kk), (unsigned short*)(ldsb + (boff) + 32768 + (p)*16384 +        tid*16)); \
  gl_lds16(gB + (size_t)((p) ? 160 : 128) * D_K + (kk), (unsigned short*)(ldsb + (boff) + 32768 + (p)*16384 + 8192 + tid*16)); \
} while (0)

// One K-tile = 4 phases. cc = this tile's buffer byte-offset, cn = other buffer.
// gA1: stage A1(tt+1); gA0/gB0/gB1: stage unit(tt+2). W: end-of-tile vmcnt count.
#define TILE_BODY(cc, cn, tt, gA1, gA0, gB0, gB1, W) do { \
    /* P0: Q00 = A0 x B0 (12 reads) */ \
    LDA_(cc, 0, afA); LDB_(cc, 0, bE); \
    if (gA1) STAGE_A_(cn, 1, ((tt)+1)*BK); \
    LGKM(8); \
    BARRIER(); LGKM(0); SCHEDB(); \
    PRIO1(); MMA_(0, 0, afA, bE); PRIO0(); \
    BARRIER(); \
    /* P1: Q01 = A0 x B1 (4 reads) */ \
    LDB_(cc, 1, bO); \
    if (gA0) STAGE_A_(cc, 0, ((tt)+2)*BK); \
    BARRIER(); LGKM(0); SCHEDB(); \
    PRIO1(); MMA_(0, 1, afA, bO); PRIO0(); \
    BARRIER(); \
    /* P2: Q11 = A1 x B1 (8 reads) */ \
    LDA_(cc, 1, afB); \
    if (gB0) STAGE_B_(cc, 0, ((tt)+2)*BK); \
    BARRIER(); LGKM(0); SCHEDB(); \
    PRIO1(); MMA_(1, 1, afB, bO); PRIO0(); \
    BARRIER(); \
    /* P3: Q10 = A1 x B0 (0 reads) */ \
    if (gB1) STAGE_B_(cc, 1, ((tt)+2)*BK); \
    BARRIER(); LGKM(0); SCHEDB(); \
    PRIO1(); MMA_(1, 0, afB, bE); PRIO0(); \
    VMCNT(W); \
    BARRIER(); \
} while (0)

__global__ __launch_bounds__(512, 2) void kgemm8(const unsigned short* __restrict__ Ab,
                                                 const unsigned short* __restrict__ Bb,
                                                 const float* __restrict__ temp,
                                                 float* __restrict__ rowsum,
                                                 float* __restrict__ colsum,
                                                 float* __restrict__ diag) {
    __shared__ __align__(128) char ldsb[131072];   // 128 KiB

    const int tid  = threadIdx.x;
    const int lane = tid & 63;
    const int wid  = tid >> 6;
    const int wm   = wid >> 2;     // 0..1
    const int wn   = wid & 3;      // 0..3

    // bijective XCD swizzle: 256 blocks = 8 XCDs x 32
    int bid = blockIdx.x;
    int swz = (bid & 7) * 32 + (bid >> 3);
    int brow = (swz >> 4) * 256;
    int bcol = (swz & 15) * 256;

    // ---- staging addresses: per-thread base + uniform row offsets ----
    const int rr = tid >> 3;                              // 0..63
    const int ch = (((tid & 7) ^ (rr & 7)) << 3);         // pre-swizzled k-chunk
    const unsigned short* gA = Ab + (size_t)(brow + rr) * D_K + ch;
    const unsigned short* gB = Bb + (size_t)(bcol + (rr >> 5) * 64 + (rr & 31)) * D_K + ch;

    // ---- ds_read constants (swizzled) ----
    const int lrow = lane & 15;
    const int kq   = lane >> 4;                 // 0..3
    const int sw   = (lane & 7) << 4;
    const int c0   = ((kq << 4)      ) ^ sw;
    const int c1   = (64 | (kq << 4)) ^ sw;
    const int abase = (wm * 64 + lrow) * 128;
    const int bbase = (wn * 32 + lrow) * 128;

    f32x4 acc[8][4];
    #pragma unroll
    for (int i = 0; i < 8; ++i)
        #pragma unroll
        for (int j = 0; j < 4; ++j) acc[i][j] = (f32x4){0.f, 0.f, 0.f, 0.f};
    bf16x8 afA[4][2];      // A0(t)
    bf16x8 afB[4][2];      // A1(t)
    bf16x8 bE[2][2];       // B0(t)
    bf16x8 bO[2][2];       // B1(t)

    // ---- prologue: tile0 all 4 units -> buf0 (oldest 8 loads); tile1 A0,B0,B1 -> buf1 ----
    STAGE_A_(0, 0, 0); STAGE_A_(0, 1, 0); STAGE_B_(0, 0, 0); STAGE_B_(0, 1, 0);
    STAGE_A_(65536, 0, BK); STAGE_B_(65536, 0, BK); STAGE_B_(65536, 1, BK);
    VMCNT(6);              // tile0's 8 loads complete; tile1's 6 may fly
    BARRIER();

    #pragma unroll 1
    for (int t = 0; t < NT - 2; t += 2) {
        TILE_BODY(0,     65536, t,     1, 1, 1, 1, 6);
        TILE_BODY(65536, 0,     t + 1, 1, 1, 1, 1, 6);
    }
    // tail pair (tiles NT-2, NT-1): only A1(NT-1) still needs staging
    TILE_BODY(0,     65536, NT - 2, 1, 0, 0, 0, 0);
    TILE_BODY(65536, 0,     NT - 1, 0, 0, 0, 0, 0);

    // ------- epilogue: relu*e^t, shifted exp, row/col partial sums, diag -------
    const float scl = expf(temp[0]);
    float cs[4] = {0.f, 0.f, 0.f, 0.f};
    #pragma unroll
    for (int mi = 0; mi < 8; ++mi) {
        float rs[4] = {0.f, 0.f, 0.f, 0.f};
        const int growb = brow + wm * 128 + (mi >> 2) * 64 + (mi & 3) * 16 + kq * 4;
        #pragma unroll
        for (int ni = 0; ni < 4; ++ni) {
            const int gc = bcol + wn * 64 + (ni >> 1) * 32 + (ni & 1) * 16 + lrow;
            #pragma unroll
            for (int j = 0; j < 4; ++j) {
                float v = fmaxf(acc[mi][ni][j], 0.f) * scl;
                if (growb + j == gc) diag[gc] = v;
                float p = expf(v - scl);
                rs[j]  += p;
                cs[ni] += p;
            }
        }
        #pragma unroll
        for (int j = 0; j < 4; ++j) {
            float v = rs[j];
            v += __shfl_xor(v, 1, 64);
            v += __shfl_xor(v, 2, 64);
            v += __shfl_xor(v, 4, 64);
            v += __shfl_xor(v, 8, 64);
            if (lrow == 0) atomicAdd(&rowsum[growb + j], v);
        }
    }
    #pragma unroll
    for (int ni = 0; ni < 4; ++ni) {
        float v = cs[ni];
        v += __shfl_xor(v, 16, 64);
        v += __shfl_xor(v, 32, 64);
        if (kq == 0) atomicAdd(&colsum[bcol + wn * 64 + (ni >> 1) * 32 + (ni & 1) * 16 + lrow], v);
    }
}

// ---------------- Kernel 3: final reduction to scalar loss ----------------
__global__ __launch_bounds__(256) void kfinal(const float* __restrict__ rowsum,
                                              const float* __restrict__ colsum,
                                              const float* __restrict__ diag,
                                              const float* __restrict__ temp,
                                              float* __restrict__ out) {
    int tid = threadIdx.x;
    float M = expf(temp[0]);
    float acc = 0.f;
    for (int i = tid; i < B_N; i += 256) {
        acc += logf(rowsum[i]) + logf(colsum[i]) + 2.f * M - 2.f * diag[i];
    }
    #pragma unroll
    for (int off = 1; off < 64; off <<= 1) acc += __shfl_xor(acc, off, 64);
    __shared__ float wsum[4];
    if ((tid & 63) == 0) wsum[tid >> 6] = acc;
    __syncthreads();
    if (tid == 0) {
        float t = wsum[0] + wsum[1] + wsum[2] + wsum[3];
        out[0] = t * (0.5f / (float)B_N);
    }
}

extern "C" void kernel_launch(void* const* d_in, const int* in_sizes, int n_in,
                              void* d_out, int out_size, void* d_ws, size_t ws_size,
                              hipStream_t stream) {
    const float* Cf   = (const float*)d_in[0];
    const float* Sf   = (const float*)d_in[1];
    const float* temp = (const float*)d_in[2];

    const size_t MATEL = (size_t)B_N * D_K;
    unsigned short* Cb = (unsigned short*)d_ws;            // 16 MB
    unsigned short* Sb = Cb + MATEL;                       // 16 MB
    float* rowsum = (float*)(Sb + MATEL);                  // 16 KB
    float* colsum = rowsum + B_N;
    float* diag   = colsum + B_N;

    hipMemsetAsync(rowsum, 0, 2 * B_N * sizeof(float), stream);
    knorm2<<<2 * B_N, 256, 0, stream>>>(Cf, Sf, Cb, Sb);
    kgemm8<<<256, 512, 0, stream>>>(Cb, Sb, temp, rowsum, colsum, diag);
    kfinal<<<1, 256, 0, stream>>>(rowsum, colsum, diag, temp, (float*)d_out);
}